// Round 16
// baseline (546.999 us; speedup 1.0000x reference)
//
#include <hip/hip_runtime.h>
#include <stdint.h>

// GATConv fused v17 = v14 (best verified, 179.4us flash) + bitmask adjacency.
// [Resubmission #2: R14/R15 benches failed with GPUAcquisitionTimeout --
//  infra (broker at capacity), not kernel. Theory and prediction unchanged.]
// R13 post-mortem: v16 delayed-PV flat (182 vs 179) -> reverted; all
// scheduling experiments (v13/v15/v16) failed; only work-removal helped.
// Counter read: flash FETCH_SIZE=156MB is ~all the A matrix (8192^2 x 4B
// = 256MB read once/launch, partially L3-absorbed). At 1.06 TB/s that is
// ~147us of HBM inside a 182us kernel, arriving in 32KB/block bursts at tile
// boundaries -> queueing + 900cy latency that 2 waves/SIMD cannot hide. A is
// BINARY: 32 bits of int32 per bit of information.
// v17: packA_kernel ballots A into an 8MB bitmask Ab[row][col/64] (bit=col&63)
// via __ballot over 64 coalesced dwords (streaming ~5TB/s ~= 45us). Flash
// reads 4 broadcast u64 loads/lane/tile instead of 16 dwords (32x traffic
// cut; Ab is L2/L3-resident). Ab reuses the Xh/Xl ws region (dead after qkv;
// packA launches after qkv -- stream-serial, safe).

typedef _Float16 f16;
typedef unsigned short u16;
typedef unsigned long long u64;
typedef __attribute__((ext_vector_type(8))) _Float16 f16x8;
typedef __attribute__((ext_vector_type(4))) _Float16 f16x4;
typedef __attribute__((ext_vector_type(4))) float f32x4;

#define NN 8192
#define DD 256
#define BR 128
#define BC 64
#define CCH 4
#define COLS (NN / CCH)  // 2048
#define NIT (COLS / BC)  // 32
#define PSTR 68          // P row stride in f16 (136 B: quad phases 0/32/64/96)
#define WPR (NN / 64)    // 128 u64 words per bitmask row

#define MFMA(a, b, c) __builtin_amdgcn_mfma_f32_16x16x32_f16((a), (b), (c), 0, 0, 0)

__device__ __forceinline__ void gl2lds16(const void* g, void* l) {
    __builtin_amdgcn_global_load_lds(
        (const __attribute__((address_space(1))) unsigned int*)g,
        (__attribute__((address_space(3))) unsigned int*)l, 16, 0, 0);
}

__device__ __forceinline__ u16 f16bits(f16 h) {
    union { f16 h; u16 u; } c;
    c.h = h;
    return c.u;
}

// 16-lane butterfly reduce on the VALU pipe (DPP), replacing ds_bpermute
// shfls (validated R4: bit-identical result, -12 VGPR).
__device__ __forceinline__ float dpp_max16(float x) {
    union { float f; int i; } a, b;
    a.f = x;
    b.i = __builtin_amdgcn_mov_dpp(a.i, 0xB1, 0xf, 0xf, true);
    a.f = fmaxf(a.f, b.f);
    b.i = __builtin_amdgcn_mov_dpp(a.i, 0x4E, 0xf, 0xf, true);
    a.f = fmaxf(a.f, b.f);
    b.i = __builtin_amdgcn_mov_dpp(a.i, 0x141, 0xf, 0xf, true);
    a.f = fmaxf(a.f, b.f);
    b.i = __builtin_amdgcn_mov_dpp(a.i, 0x140, 0xf, 0xf, true);
    a.f = fmaxf(a.f, b.f);
    return a.f;
}

__device__ __forceinline__ float dpp_sum16(float x) {
    union { float f; int i; } a, b;
    a.f = x;
    b.i = __builtin_amdgcn_mov_dpp(a.i, 0xB1, 0xf, 0xf, true);
    a.f += b.f;
    b.i = __builtin_amdgcn_mov_dpp(a.i, 0x4E, 0xf, 0xf, true);
    a.f += b.f;
    b.i = __builtin_amdgcn_mov_dpp(a.i, 0x141, 0xf, 0xf, true);
    a.f += b.f;
    b.i = __builtin_amdgcn_mov_dpp(a.i, 0x140, 0xf, 0xf, true);
    a.f += b.f;
    return a.f;
}

// ---------------- split X to fp16 hi/lo (4 elems/thread) ----------------
__global__ void splitX_kernel(const float4* __restrict__ X, f16x4* __restrict__ Xh,
                              f16x4* __restrict__ Xl) {
    const int i = blockIdx.x * blockDim.x + threadIdx.x;  // 524288
    const float4 v = X[i];
    const f16 h0 = (f16)v.x, h1 = (f16)v.y, h2 = (f16)v.z, h3 = (f16)v.w;
    f16x4 H = {h0, h1, h2, h3};
    f16x4 L = {(f16)(v.x - (float)h0), (f16)(v.y - (float)h1), (f16)(v.z - (float)h2),
               (f16)(v.w - (float)h3)};
    Xh[i] = H;
    Xl[i] = L;
}

// W[k][n] (3 mats 256x256) -> Wt[(mat*256+n)][k] fp16 hi/lo (transposed)
__global__ void splitW_kernel(const float* __restrict__ Wq, const float* __restrict__ Wk,
                              const float* __restrict__ Wv, f16* __restrict__ WtH,
                              f16* __restrict__ WtL) {
    const int i = blockIdx.x * blockDim.x + threadIdx.x;  // 3*65536
    const int mat = i >> 16;
    const int k = (i >> 8) & 255;
    const int n = i & 255;
    const float* W = (mat == 0) ? Wq : ((mat == 1) ? Wk : Wv);
    const float v = W[k * 256 + n];
    const f16 h = (f16)v;
    const size_t o = (size_t)(mat * 256 + n) * 256 + k;
    WtH[o] = h;
    WtL[o] = (f16)(v - (float)h);
}

// ---------------- pack A (int32 0/1) into bitmask Ab[row][col/64] ----------------
// One wave-task: 256 cols of one row -> 4 ballots (64 coalesced dwords each)
// -> 4 u64 (natural bit order: bit l of word w = A[row][w*64 + l]).
__global__ __launch_bounds__(256) void packA_kernel(const int* __restrict__ A,
                                                    u64* __restrict__ Ab) {
    const int lane = threadIdx.x & 63;
    const int wv = (blockIdx.x * blockDim.x + threadIdx.x) >> 6;  // global wave
    const int nw = (gridDim.x * blockDim.x) >> 6;
#pragma unroll 1
    for (int t = wv; t < (NN * NN / 256); t += nw) {
        const int r = t >> 5;   // row
        const int sp = t & 31;  // 256-col span
        const size_t base = (size_t)r * NN + sp * 256;
        u64 b0 = __ballot(A[base + 0 * 64 + lane] != 0);
        u64 b1 = __ballot(A[base + 1 * 64 + lane] != 0);
        u64 b2 = __ballot(A[base + 2 * 64 + lane] != 0);
        u64 b3 = __ballot(A[base + 3 * 64 + lane] != 0);
        u64 v = b0;
        if ((lane & 3) == 1) v = b1;
        if ((lane & 3) == 2) v = b2;
        if ((lane & 3) == 3) v = b3;
        if (lane < 4) Ab[(size_t)r * WPR + sp * 4 + lane] = v;
    }
}

// ---------------- QKV GEMM: LDS-staged W chunks, X frags in registers ----------------
__global__ __launch_bounds__(256, 2) void qkv_kernel(
    const f16* __restrict__ Xh, const f16* __restrict__ Xl,
    const f16* __restrict__ WtH, const f16* __restrict__ WtL,
    f16* __restrict__ Qh, f16* __restrict__ Ql,
    f16* __restrict__ Kh, f16* __restrict__ Vt) {
    __shared__ f16 Wh[64 * 256];
    __shared__ f16 Wl[64 * 256];
    const int lane = threadIdx.x & 63;
    const int w = threadIdx.x >> 6;
    const int l15 = lane & 15;
    const int quad = lane >> 4;
    const int r0 = blockIdx.x * 64;
    const int mat = blockIdx.y;

    f16x8 xh[8], xl[8];
    const size_t xb = (size_t)(r0 + w * 16 + l15) * DD + quad * 8;
#pragma unroll
    for (int kc = 0; kc < 8; ++kc) {
        xh[kc] = *(const f16x8*)(Xh + xb + kc * 32);
        xl[kc] = *(const f16x8*)(Xl + xb + kc * 32);
    }
    const int orow = r0 + w * 16 + quad * 4;

#pragma unroll 1
    for (int c = 0; c < 4; ++c) {
        const int nb = mat * 256 + c * 64;
#pragma unroll
        for (int i = 0; i < 8; ++i) {
            const int r = w * 16 + i * 2 + (lane >> 5);
            gl2lds16(WtH + (size_t)(nb + r) * DD + (((lane & 31) ^ (r & 7)) * 8),
                     &Wh[(w * 16 + i * 2) * 256]);
        }
#pragma unroll
        for (int i = 0; i < 8; ++i) {
            const int r = w * 16 + i * 2 + (lane >> 5);
            gl2lds16(WtL + (size_t)(nb + r) * DD + (((lane & 31) ^ (r & 7)) * 8),
                     &Wl[(w * 16 + i * 2) * 256]);
        }
        __syncthreads();

        const f32x4 fzero = {0.f, 0.f, 0.f, 0.f};
        f32x4 acc[4];
#pragma unroll
        for (int nt = 0; nt < 4; ++nt) acc[nt] = fzero;
#pragma unroll
        for (int kc = 0; kc < 8; ++kc)
#pragma unroll
            for (int nt = 0; nt < 4; ++nt) {
                const int r = nt * 16 + l15;
                const int blk = (((kc * 4 + quad) ^ (r & 7)) * 8);
                const f16x8 wh = *(const f16x8*)&Wh[r * 256 + blk];
                const f16x8 wl = *(const f16x8*)&Wl[r * 256 + blk];
                acc[nt] = MFMA(xh[kc], wh, acc[nt]);
                acc[nt] = MFMA(xh[kc], wl, acc[nt]);
                acc[nt] = MFMA(xl[kc], wh, acc[nt]);
            }

        if (mat == 0) {
#pragma unroll
            for (int nt = 0; nt < 4; ++nt)
#pragma unroll
                for (int rg = 0; rg < 4; ++rg) {
                    const int col = c * 64 + nt * 16 + l15;
                    const float v = acc[nt][rg];
                    const f16 h = (f16)v;
                    Qh[(size_t)(orow + rg) * DD + col] = h;
                    Ql[(size_t)(orow + rg) * DD + col] = (f16)(v - (float)h);
                }
        } else if (mat == 1) {
#pragma unroll
            for (int nt = 0; nt < 4; ++nt)
#pragma unroll
                for (int rg = 0; rg < 4; ++rg) {
                    const int col = c * 64 + nt * 16 + l15;
                    Kh[(size_t)(orow + rg) * DD + col] = (f16)acc[nt][rg];
                }
        } else {
#pragma unroll
            for (int nt = 0; nt < 4; ++nt) {
                const int n = c * 64 + nt * 16 + l15;
                ushort4 pk;
                pk.x = f16bits((f16)acc[nt][0]);
                pk.y = f16bits((f16)acc[nt][1]);
                pk.z = f16bits((f16)acc[nt][2]);
                pk.w = f16bits((f16)acc[nt][3]);
                *(ushort4*)(Vt + (size_t)n * NN + orow) = pk;
            }
        }
        __syncthreads();
    }
}

// ---------------- flash kernel v17 (v14 structure + bitmask adjacency) ----------
// grid 256 linear: cch = bid&3 (pins chunk to XCD pair), rowblk = bid>>2, BR=128.
__global__ __launch_bounds__(512, 2) void flash_kernel(
    const f16* __restrict__ Qh, const f16* __restrict__ Ql,
    const f16* __restrict__ Kh, const f16* __restrict__ Vt,
    const u64* __restrict__ Ab,
    float* __restrict__ pO, float* __restrict__ pM, float* __restrict__ pL) {
    __shared__ f16 Klds[2][64 * 256];   // 64 KB dbuf, [j][k] XOR-swizzled by j&7
    __shared__ f16 Vlds[2][256 * 64];   // 64 KB dbuf, [n][j] swizzled by n&7
    __shared__ f16 Plds[8][16 * PSTR];  // 17 KB, per-wave, stride 68 (bank-clean)

    const int lane = threadIdx.x & 63;
    const int w = threadIdx.x >> 6;  // 0..7
    const int l15 = lane & 15;
    const int quad = lane >> 4;
    const int bid = blockIdx.x;
    const int cch = bid & 3;
    const int r0 = (bid >> 2) * BR;
    const int col0 = cch * COLS;

    // Q fragments resident (A-layout m=l15, k=quad*8+i), hi+lo
    f16x8 qh[8], ql[8];
    {
        const size_t qb = (size_t)(r0 + w * 16 + l15) * DD + quad * 8;
#pragma unroll
        for (int kc = 0; kc < 8; ++kc) {
            qh[kc] = *(const f16x8*)(Qh + qb + kc * 32);
            ql[kc] = *(const f16x8*)(Ql + qb + kc * 32);
        }
    }

    const f32x4 fzero = {0.f, 0.f, 0.f, 0.f};
    f32x4 accO[16];
#pragma unroll
    for (int i = 0; i < 16; ++i) accO[i] = fzero;
    float mrow[4], lpart[4];  // lpart: per-LANE partials, reduced in epilogue
#pragma unroll
    for (int r = 0; r < 4; ++r) {
        mrow[r] = -1e30f;
        lpart[r] = 0.f;
    }
    const int growb = r0 + w * 16 + quad * 4;
    f16* Pw = &Plds[w][0];

    // stage tile `t` into buffer `b` (each of 8 waves: 4 K-instrs + 4 V-instrs)
    auto stage = [&](int t, int b) {
        const int j0 = col0 + t * BC;
#pragma unroll
        for (int i = 0; i < 4; ++i) {
            const int r = w * 8 + i * 2 + (lane >> 5);
            gl2lds16(Kh + (size_t)(j0 + r) * DD + (((lane & 31) ^ (r & 7)) * 8),
                     &Klds[b][(w * 8 + i * 2) * 256]);
        }
#pragma unroll
        for (int i = 0; i < 4; ++i) {
            const int n = w * 32 + i * 8 + (lane >> 3);
            gl2lds16(Vt + (size_t)n * NN + j0 + (((lane & 7) ^ (n & 7)) * 8),
                     &Vlds[b][(w * 32 + i * 8) * 64]);
        }
    };

    // prologue: stage tile 0 -> buf 0
    stage(0, 0);
    __syncthreads();

#pragma unroll 1
    for (int it = 0; it < NIT; ++it) {
        const int cur = it & 1;
        const int j0 = col0 + it * BC;

        // stage NEXT tile into alternate buffer (covered by this iter's compute)
        if (it + 1 < NIT) stage(it + 1, cur ^ 1);

        // adjacency bits for this tile from packed Ab (8MB, L2/L3-resident).
        // 4 broadcast u64 loads/lane (quads share address) vs v14's 16 dwords:
        // 32x HBM traffic cut (256MB -> 8MB per launch).
        u64 am[4];
        const int wrd = col0 / 64 + it;
#pragma unroll
        for (int rgi = 0; rgi < 4; ++rgi)
            am[rgi] = Ab[(size_t)(growb + rgi) * WPR + wrd];

        // S = (Qh+Ql)·Kh^T : 16 rows x 64 cols per wave
        f32x4 accS[4];
#pragma unroll
        for (int jt = 0; jt < 4; ++jt) accS[jt] = fzero;
        __builtin_amdgcn_s_setprio(1);
#pragma unroll
        for (int kc = 0; kc < 8; ++kc)
#pragma unroll
            for (int jt = 0; jt < 4; ++jt) {
                const int r = jt * 16 + l15;
                const f16x8 kf =
                    *(const f16x8*)&Klds[cur][r * 256 + (((kc * 4 + quad) ^ (r & 7)) * 8)];
                accS[jt] = MFMA(qh[kc], kf, accS[jt]);
                accS[jt] = MFMA(ql[kc], kf, accS[jt]);
            }
        __builtin_amdgcn_s_setprio(0);

        // wave-local online softmax (DPP max reduce; exact defer-rescale)
#pragma unroll
        for (int rgi = 0; rgi < 4; ++rgi) {
            const int gr = growb + rgi;
            const unsigned int mlo = (unsigned int)am[rgi];
            const unsigned int mhi = (unsigned int)(am[rgi] >> 32);
            float mx = -3.0e38f;
#pragma unroll
            for (int jt = 0; jt < 4; ++jt) {
                const int gc = j0 + jt * 16 + l15;
                const unsigned int mw = (jt < 2) ? mlo : mhi;
                const int bit = (mw >> ((jt & 1) * 16 + l15)) & 1;
                const float s = (bit != 0 || gr == gc) ? accS[jt][rgi] : -3.0e38f;
                accS[jt][rgi] = s;
                mx = fmaxf(mx, s);
            }
            mx = dpp_max16(mx);
            const float mnew = fmaxf(mrow[rgi], mx);
            if (__any(mnew > mrow[rgi])) {
                const float al = __expf(mrow[rgi] - mnew);
                mrow[rgi] = mnew;
                lpart[rgi] *= al;
#pragma unroll
                for (int nt = 0; nt < 16; ++nt) accO[nt][rgi] *= al;
            }
            float rs = 0.f;
            const int row = quad * 4 + rgi;
#pragma unroll
            for (int jt = 0; jt < 4; ++jt) {
                const float s = accS[jt][rgi];
                const float e = (s > -1.0e37f) ? __expf(s - mrow[rgi]) : 0.f;
                rs += e;
                Pw[row * PSTR + jt * 16 + l15] = (f16)e;
            }
            lpart[rgi] += rs;  // per-lane; epilogue reduce
        }

        // P A-frags (per-wave LDS round trip; in-order LDS pipe, no barrier)
        f16x8 pf[2];
        pf[0] = *(const f16x8*)&Pw[l15 * PSTR + quad * 8];
        pf[1] = *(const f16x8*)&Pw[l15 * PSTR + 32 + quad * 8];

        // PV: 16 rows x 256 n per wave
        __builtin_amdgcn_s_setprio(1);
#pragma unroll
        for (int nt = 0; nt < 16; ++nt)
#pragma unroll
            for (int kc2 = 0; kc2 < 2; ++kc2) {
                const int n = nt * 16 + l15;
                const f16x8 vf =
                    *(const f16x8*)&Vlds[cur][n * 64 + (((kc2 * 4 + quad) ^ (n & 7)) * 8)];
                accO[nt] = MFMA(pf[kc2], vf, accO[nt]);
            }
        __builtin_amdgcn_s_setprio(0);

        // single barrier: compute(it) done before buf overwrite; drains stage(it+1)
        __syncthreads();
    }

    // epilogue: reduce per-lane l partials across 16 lanes (DPP, once)
#pragma unroll
    for (int rgi = 0; rgi < 4; ++rgi) lpart[rgi] = dpp_sum16(lpart[rgi]);

    // write partials
#pragma unroll
    for (int nt = 0; nt < 16; ++nt)
#pragma unroll
        for (int rgi = 0; rgi < 4; ++rgi)
            pO[((size_t)cch * NN + growb + rgi) * DD + nt * 16 + l15] = accO[nt][rgi];
    if (l15 == 0) {
#pragma unroll
        for (int rgi = 0; rgi < 4; ++rgi) {
            pM[(size_t)cch * NN + growb + rgi] = mrow[rgi];
            pL[(size_t)cch * NN + growb + rgi] = lpart[rgi];
        }
    }
}

// ---------------- merge partials (8 rows/block) ----------------
__global__ __launch_bounds__(256) void merge_kernel(const float* __restrict__ pO,
                                                    const float* __restrict__ pM,
                                                    const float* __restrict__ pL,
                                                    float* __restrict__ out) {
    const int n = threadIdx.x;
#pragma unroll 1
    for (int rr = 0; rr < 8; ++rr) {
        const int row = blockIdx.x * 8 + rr;
        float mc[CCH], lc[CCH];
        float M = -3e38f;
#pragma unroll
        for (int c = 0; c < CCH; ++c) {
            mc[c] = pM[(size_t)c * NN + row];
            lc[c] = pL[(size_t)c * NN + row];
            M = fmaxf(M, mc[c]);
        }
        float L = 0.f, acc = 0.f;
#pragma unroll
        for (int c = 0; c < CCH; ++c) {
            const float wgt = __expf(mc[c] - M);
            L += wgt * lc[c];
            acc += wgt * pO[((size_t)c * NN + row) * DD + n];
        }
        out[(size_t)row * DD + n] = acc / L;
    }
}

extern "C" void kernel_launch(void* const* d_in, const int* in_sizes, int n_in,
                              void* d_out, int out_size, void* d_ws, size_t ws_size,
                              hipStream_t stream) {
    const float* X = (const float*)d_in[0];
    const int* A = (const int*)d_in[1];
    const float* Wq = (const float*)d_in[2];
    const float* Wk = (const float*)d_in[3];
    const float* Wv = (const float*)d_in[4];
    float* out = (float*)d_out;

    char* ws = (char*)d_ws;
    const size_t MB = 1ull << 20;
    f16* Xh = (f16*)(ws + 0 * MB);
    f16* Xl = (f16*)(ws + 4 * MB);
    f16* WtH = (f16*)(ws + 8 * MB);
    f16* WtL = (f16*)(ws + 8 * MB + 512 * 1024);
    f16* Qh = (f16*)(ws + 9 * MB);
    f16* Ql = (f16*)(ws + 13 * MB);
    f16* Kh = (f16*)(ws + 17 * MB);
    f16* Vt = (f16*)(ws + 21 * MB);
    float* pO = (float*)(ws + 25 * MB);
    float* pM = (float*)(ws + 57 * MB);
    float* pL = (float*)(ws + 57 * MB + 256 * 1024);
    // Ab (8MB bitmask) reuses the Xh/Xl region -- dead after qkv_kernel,
    // and packA launches after qkv (stream-serial, graph-safe).
    u64* Ab = (u64*)(ws + 0 * MB);
    (void)ws_size; (void)in_sizes; (void)n_in; (void)out_size;

    splitX_kernel<<<2048, 256, 0, stream>>>((const float4*)X, (f16x4*)Xh, (f16x4*)Xl);
    splitW_kernel<<<768, 256, 0, stream>>>(Wq, Wk, Wv, WtH, WtL);
    qkv_kernel<<<dim3(NN / 64, 3), 256, 0, stream>>>(Xh, Xl, WtH, WtL, Qh, Ql, Kh, Vt);
    packA_kernel<<<2048, 256, 0, stream>>>(A, Ab);
    flash_kernel<<<(NN / BR) * CCH, 512, 0, stream>>>(Qh, Ql, Kh, Vt, Ab, pO, pM, pL);
    merge_kernel<<<NN / 8, 256, 0, stream>>>(pO, pM, pL, out);
}

// Round 17
// 494.700 us; speedup vs baseline: 1.1057x; 1.1057x over previous
//
#include <hip/hip_runtime.h>
#include <stdint.h>

// GATConv fused v18 = v14 restored (best verified: 494.9us total, 179.4us
// flash) + splitX/splitW fused into one prep kernel (one fewer launch).
// R16 post-mortem: v17 bitmask was half-right -- flash FETCH 156->28.7MB and
// dur 179->167 (A-traffic was real), but packA cost ~64us serial for a 12us
// flash gain: A has NO read-redundancy (each element read once by its owning
// block), so in-flash A reads overlapping compute (+12us marginal) beat any
// dedicated packing pass (>=40us). Reverted to v14's A handling.
// Cross-round ledger: total - flash ~= 315us INVARIANT across v12-v17; the
// aux kernels should cost <60us by traffic arithmetic -> residual unexplained.
// v18 probes it: fuse the two split kernels (block-partitioned, identical
// numerics). If total drops, residual is launch/graph overhead; if flat at
// ~495, residual is inside qkv/merge -> attack those next.

typedef _Float16 f16;
typedef unsigned short u16;
typedef __attribute__((ext_vector_type(8))) _Float16 f16x8;
typedef __attribute__((ext_vector_type(4))) _Float16 f16x4;
typedef __attribute__((ext_vector_type(4))) float f32x4;

#define NN 8192
#define DD 256
#define BR 128
#define BC 64
#define CCH 4
#define COLS (NN / CCH)  // 2048
#define NIT (COLS / BC)  // 32
#define PSTR 68          // P row stride in f16 (136 B: quad phases 0/32/64/96)

#define MFMA(a, b, c) __builtin_amdgcn_mfma_f32_16x16x32_f16((a), (b), (c), 0, 0, 0)

__device__ __forceinline__ void gl2lds16(const void* g, void* l) {
    __builtin_amdgcn_global_load_lds(
        (const __attribute__((address_space(1))) unsigned int*)g,
        (__attribute__((address_space(3))) unsigned int*)l, 16, 0, 0);
}

__device__ __forceinline__ u16 f16bits(f16 h) {
    union { f16 h; u16 u; } c;
    c.h = h;
    return c.u;
}

// 16-lane butterfly reduce on the VALU pipe (DPP), replacing ds_bpermute
// shfls (validated R4: bit-identical result, -12 VGPR).
__device__ __forceinline__ float dpp_max16(float x) {
    union { float f; int i; } a, b;
    a.f = x;
    b.i = __builtin_amdgcn_mov_dpp(a.i, 0xB1, 0xf, 0xf, true);
    a.f = fmaxf(a.f, b.f);
    b.i = __builtin_amdgcn_mov_dpp(a.i, 0x4E, 0xf, 0xf, true);
    a.f = fmaxf(a.f, b.f);
    b.i = __builtin_amdgcn_mov_dpp(a.i, 0x141, 0xf, 0xf, true);
    a.f = fmaxf(a.f, b.f);
    b.i = __builtin_amdgcn_mov_dpp(a.i, 0x140, 0xf, 0xf, true);
    a.f = fmaxf(a.f, b.f);
    return a.f;
}

__device__ __forceinline__ float dpp_sum16(float x) {
    union { float f; int i; } a, b;
    a.f = x;
    b.i = __builtin_amdgcn_mov_dpp(a.i, 0xB1, 0xf, 0xf, true);
    a.f += b.f;
    b.i = __builtin_amdgcn_mov_dpp(a.i, 0x4E, 0xf, 0xf, true);
    a.f += b.f;
    b.i = __builtin_amdgcn_mov_dpp(a.i, 0x141, 0xf, 0xf, true);
    a.f += b.f;
    b.i = __builtin_amdgcn_mov_dpp(a.i, 0x140, 0xf, 0xf, true);
    a.f += b.f;
    return a.f;
}

// ---------------- fused prep: splitX (blocks 0..2047) + splitW (2048..2815) ----
// X: 8192x256 f32 -> Xh/Xl f16 hi/lo (4 elems/thread).
// W: 3 mats 256x256 -> Wt[(mat*256+n)][k] f16 hi/lo (transposed).
__global__ __launch_bounds__(256) void prep_kernel(
    const float4* __restrict__ X, f16x4* __restrict__ Xh, f16x4* __restrict__ Xl,
    const float* __restrict__ Wq, const float* __restrict__ Wk,
    const float* __restrict__ Wv, f16* __restrict__ WtH, f16* __restrict__ WtL) {
    const int bid = blockIdx.x;
    if (bid < 2048) {
        const int i = bid * 256 + threadIdx.x;  // 524288
        const float4 v = X[i];
        const f16 h0 = (f16)v.x, h1 = (f16)v.y, h2 = (f16)v.z, h3 = (f16)v.w;
        f16x4 H = {h0, h1, h2, h3};
        f16x4 L = {(f16)(v.x - (float)h0), (f16)(v.y - (float)h1),
                   (f16)(v.z - (float)h2), (f16)(v.w - (float)h3)};
        Xh[i] = H;
        Xl[i] = L;
    } else {
        const int i = (bid - 2048) * 256 + threadIdx.x;  // 3*65536
        const int mat = i >> 16;
        const int k = (i >> 8) & 255;
        const int n = i & 255;
        const float* W = (mat == 0) ? Wq : ((mat == 1) ? Wk : Wv);
        const float v = W[k * 256 + n];
        const f16 h = (f16)v;
        const size_t o = (size_t)(mat * 256 + n) * 256 + k;
        WtH[o] = h;
        WtL[o] = (f16)(v - (float)h);
    }
}

// ---------------- QKV GEMM: LDS-staged W chunks, X frags in registers ----------------
__global__ __launch_bounds__(256, 2) void qkv_kernel(
    const f16* __restrict__ Xh, const f16* __restrict__ Xl,
    const f16* __restrict__ WtH, const f16* __restrict__ WtL,
    f16* __restrict__ Qh, f16* __restrict__ Ql,
    f16* __restrict__ Kh, f16* __restrict__ Vt) {
    __shared__ f16 Wh[64 * 256];
    __shared__ f16 Wl[64 * 256];
    const int lane = threadIdx.x & 63;
    const int w = threadIdx.x >> 6;
    const int l15 = lane & 15;
    const int quad = lane >> 4;
    const int r0 = blockIdx.x * 64;
    const int mat = blockIdx.y;

    f16x8 xh[8], xl[8];
    const size_t xb = (size_t)(r0 + w * 16 + l15) * DD + quad * 8;
#pragma unroll
    for (int kc = 0; kc < 8; ++kc) {
        xh[kc] = *(const f16x8*)(Xh + xb + kc * 32);
        xl[kc] = *(const f16x8*)(Xl + xb + kc * 32);
    }
    const int orow = r0 + w * 16 + quad * 4;

#pragma unroll 1
    for (int c = 0; c < 4; ++c) {
        const int nb = mat * 256 + c * 64;
#pragma unroll
        for (int i = 0; i < 8; ++i) {
            const int r = w * 16 + i * 2 + (lane >> 5);
            gl2lds16(WtH + (size_t)(nb + r) * DD + (((lane & 31) ^ (r & 7)) * 8),
                     &Wh[(w * 16 + i * 2) * 256]);
        }
#pragma unroll
        for (int i = 0; i < 8; ++i) {
            const int r = w * 16 + i * 2 + (lane >> 5);
            gl2lds16(WtL + (size_t)(nb + r) * DD + (((lane & 31) ^ (r & 7)) * 8),
                     &Wl[(w * 16 + i * 2) * 256]);
        }
        __syncthreads();

        const f32x4 fzero = {0.f, 0.f, 0.f, 0.f};
        f32x4 acc[4];
#pragma unroll
        for (int nt = 0; nt < 4; ++nt) acc[nt] = fzero;
#pragma unroll
        for (int kc = 0; kc < 8; ++kc)
#pragma unroll
            for (int nt = 0; nt < 4; ++nt) {
                const int r = nt * 16 + l15;
                const int blk = (((kc * 4 + quad) ^ (r & 7)) * 8);
                const f16x8 wh = *(const f16x8*)&Wh[r * 256 + blk];
                const f16x8 wl = *(const f16x8*)&Wl[r * 256 + blk];
                acc[nt] = MFMA(xh[kc], wh, acc[nt]);
                acc[nt] = MFMA(xh[kc], wl, acc[nt]);
                acc[nt] = MFMA(xl[kc], wh, acc[nt]);
            }

        if (mat == 0) {
#pragma unroll
            for (int nt = 0; nt < 4; ++nt)
#pragma unroll
                for (int rg = 0; rg < 4; ++rg) {
                    const int col = c * 64 + nt * 16 + l15;
                    const float v = acc[nt][rg];
                    const f16 h = (f16)v;
                    Qh[(size_t)(orow + rg) * DD + col] = h;
                    Ql[(size_t)(orow + rg) * DD + col] = (f16)(v - (float)h);
                }
        } else if (mat == 1) {
#pragma unroll
            for (int nt = 0; nt < 4; ++nt)
#pragma unroll
                for (int rg = 0; rg < 4; ++rg) {
                    const int col = c * 64 + nt * 16 + l15;
                    Kh[(size_t)(orow + rg) * DD + col] = (f16)acc[nt][rg];
                }
        } else {
#pragma unroll
            for (int nt = 0; nt < 4; ++nt) {
                const int n = c * 64 + nt * 16 + l15;
                ushort4 pk;
                pk.x = f16bits((f16)acc[nt][0]);
                pk.y = f16bits((f16)acc[nt][1]);
                pk.z = f16bits((f16)acc[nt][2]);
                pk.w = f16bits((f16)acc[nt][3]);
                *(ushort4*)(Vt + (size_t)n * NN + orow) = pk;
            }
        }
        __syncthreads();
    }
}

// ---------------- flash kernel v14 (verified best: DPP reduce + PSTR 68) ----------
// grid 256 linear: cch = bid&3 (pins chunk to XCD pair), rowblk = bid>>2, BR=128.
__global__ __launch_bounds__(512, 2) void flash_kernel(
    const f16* __restrict__ Qh, const f16* __restrict__ Ql,
    const f16* __restrict__ Kh, const f16* __restrict__ Vt,
    const int* __restrict__ A,
    float* __restrict__ pO, float* __restrict__ pM, float* __restrict__ pL) {
    __shared__ f16 Klds[2][64 * 256];   // 64 KB dbuf, [j][k] XOR-swizzled by j&7
    __shared__ f16 Vlds[2][256 * 64];   // 64 KB dbuf, [n][j] swizzled by n&7
    __shared__ f16 Plds[8][16 * PSTR];  // 17 KB, per-wave, stride 68 (bank-clean)

    const int lane = threadIdx.x & 63;
    const int w = threadIdx.x >> 6;  // 0..7
    const int l15 = lane & 15;
    const int quad = lane >> 4;
    const int bid = blockIdx.x;
    const int cch = bid & 3;
    const int r0 = (bid >> 2) * BR;
    const int col0 = cch * COLS;

    // Q fragments resident (A-layout m=l15, k=quad*8+i), hi+lo
    f16x8 qh[8], ql[8];
    {
        const size_t qb = (size_t)(r0 + w * 16 + l15) * DD + quad * 8;
#pragma unroll
        for (int kc = 0; kc < 8; ++kc) {
            qh[kc] = *(const f16x8*)(Qh + qb + kc * 32);
            ql[kc] = *(const f16x8*)(Ql + qb + kc * 32);
        }
    }

    const f32x4 fzero = {0.f, 0.f, 0.f, 0.f};
    f32x4 accO[16];
#pragma unroll
    for (int i = 0; i < 16; ++i) accO[i] = fzero;
    float mrow[4], lpart[4];  // lpart: per-LANE partials, reduced in epilogue
#pragma unroll
    for (int r = 0; r < 4; ++r) {
        mrow[r] = -1e30f;
        lpart[r] = 0.f;
    }
    const int growb = r0 + w * 16 + quad * 4;
    f16* Pw = &Plds[w][0];

    // stage tile `t` into buffer `b` (each of 8 waves: 4 K-instrs + 4 V-instrs)
    auto stage = [&](int t, int b) {
        const int j0 = col0 + t * BC;
#pragma unroll
        for (int i = 0; i < 4; ++i) {
            const int r = w * 8 + i * 2 + (lane >> 5);
            gl2lds16(Kh + (size_t)(j0 + r) * DD + (((lane & 31) ^ (r & 7)) * 8),
                     &Klds[b][(w * 8 + i * 2) * 256]);
        }
#pragma unroll
        for (int i = 0; i < 4; ++i) {
            const int n = w * 32 + i * 8 + (lane >> 3);
            gl2lds16(Vt + (size_t)n * NN + j0 + (((lane & 7) ^ (n & 7)) * 8),
                     &Vlds[b][(w * 32 + i * 8) * 64]);
        }
    };

    // prologue: stage tile 0 -> buf 0
    stage(0, 0);
    __syncthreads();

#pragma unroll 1
    for (int it = 0; it < NIT; ++it) {
        const int cur = it & 1;
        const int j0 = col0 + it * BC;

        // stage NEXT tile into alternate buffer (covered by this iter's compute)
        if (it + 1 < NIT) stage(it + 1, cur ^ 1);

        // adjacency for this tile (nontemporal: streamed once; overlaps QK)
        int av[4][4];
#pragma unroll
        for (int rgi = 0; rgi < 4; ++rgi)
#pragma unroll
            for (int jt = 0; jt < 4; ++jt)
                av[rgi][jt] = __builtin_nontemporal_load(
                    A + (size_t)(growb + rgi) * NN + j0 + jt * 16 + l15);

        // S = (Qh+Ql)·Kh^T : 16 rows x 64 cols per wave
        f32x4 accS[4];
#pragma unroll
        for (int jt = 0; jt < 4; ++jt) accS[jt] = fzero;
        __builtin_amdgcn_s_setprio(1);
#pragma unroll
        for (int kc = 0; kc < 8; ++kc)
#pragma unroll
            for (int jt = 0; jt < 4; ++jt) {
                const int r = jt * 16 + l15;
                const f16x8 kf =
                    *(const f16x8*)&Klds[cur][r * 256 + (((kc * 4 + quad) ^ (r & 7)) * 8)];
                accS[jt] = MFMA(qh[kc], kf, accS[jt]);
                accS[jt] = MFMA(ql[kc], kf, accS[jt]);
            }
        __builtin_amdgcn_s_setprio(0);

        // wave-local online softmax (DPP max reduce -- VALU pipe, not LDS;
        // exact defer-rescale: alpha==1 path skipped, bitwise-identical)
#pragma unroll
        for (int rgi = 0; rgi < 4; ++rgi) {
            const int gr = growb + rgi;
            float mx = -3.0e38f;
#pragma unroll
            for (int jt = 0; jt < 4; ++jt) {
                const int gc = j0 + jt * 16 + l15;
                const float s = (av[rgi][jt] != 0 || gr == gc) ? accS[jt][rgi] : -3.0e38f;
                accS[jt][rgi] = s;
                mx = fmaxf(mx, s);
            }
            mx = dpp_max16(mx);
            const float mnew = fmaxf(mrow[rgi], mx);
            if (__any(mnew > mrow[rgi])) {
                const float al = __expf(mrow[rgi] - mnew);
                mrow[rgi] = mnew;
                lpart[rgi] *= al;
#pragma unroll
                for (int nt = 0; nt < 16; ++nt) accO[nt][rgi] *= al;
            }
            float rs = 0.f;
            const int row = quad * 4 + rgi;
#pragma unroll
            for (int jt = 0; jt < 4; ++jt) {
                const float s = accS[jt][rgi];
                const float e = (s > -1.0e37f) ? __expf(s - mrow[rgi]) : 0.f;
                rs += e;
                Pw[row * PSTR + jt * 16 + l15] = (f16)e;
            }
            lpart[rgi] += rs;  // per-lane; epilogue reduce
        }

        // P A-frags (per-wave LDS round trip; in-order LDS pipe, no barrier)
        f16x8 pf[2];
        pf[0] = *(const f16x8*)&Pw[l15 * PSTR + quad * 8];
        pf[1] = *(const f16x8*)&Pw[l15 * PSTR + 32 + quad * 8];

        // PV: 16 rows x 256 n per wave
        __builtin_amdgcn_s_setprio(1);
#pragma unroll
        for (int nt = 0; nt < 16; ++nt)
#pragma unroll
            for (int kc2 = 0; kc2 < 2; ++kc2) {
                const int n = nt * 16 + l15;
                const f16x8 vf =
                    *(const f16x8*)&Vlds[cur][n * 64 + (((kc2 * 4 + quad) ^ (n & 7)) * 8)];
                accO[nt] = MFMA(pf[kc2], vf, accO[nt]);
            }
        __builtin_amdgcn_s_setprio(0);

        // single barrier: compute(it) done before buf overwrite; drains stage(it+1)
        __syncthreads();
    }

    // epilogue: reduce per-lane l partials across 16 lanes (DPP, once)
#pragma unroll
    for (int rgi = 0; rgi < 4; ++rgi) lpart[rgi] = dpp_sum16(lpart[rgi]);

    // write partials
#pragma unroll
    for (int nt = 0; nt < 16; ++nt)
#pragma unroll
        for (int rgi = 0; rgi < 4; ++rgi)
            pO[((size_t)cch * NN + growb + rgi) * DD + nt * 16 + l15] = accO[nt][rgi];
    if (l15 == 0) {
#pragma unroll
        for (int rgi = 0; rgi < 4; ++rgi) {
            pM[(size_t)cch * NN + growb + rgi] = mrow[rgi];
            pL[(size_t)cch * NN + growb + rgi] = lpart[rgi];
        }
    }
}

// ---------------- merge partials (8 rows/block) ----------------
__global__ __launch_bounds__(256) void merge_kernel(const float* __restrict__ pO,
                                                    const float* __restrict__ pM,
                                                    const float* __restrict__ pL,
                                                    float* __restrict__ out) {
    const int n = threadIdx.x;
#pragma unroll 1
    for (int rr = 0; rr < 8; ++rr) {
        const int row = blockIdx.x * 8 + rr;
        float mc[CCH], lc[CCH];
        float M = -3e38f;
#pragma unroll
        for (int c = 0; c < CCH; ++c) {
            mc[c] = pM[(size_t)c * NN + row];
            lc[c] = pL[(size_t)c * NN + row];
            M = fmaxf(M, mc[c]);
        }
        float L = 0.f, acc = 0.f;
#pragma unroll
        for (int c = 0; c < CCH; ++c) {
            const float wgt = __expf(mc[c] - M);
            L += wgt * lc[c];
            acc += wgt * pO[((size_t)c * NN + row) * DD + n];
        }
        out[(size_t)row * DD + n] = acc / L;
    }
}

extern "C" void kernel_launch(void* const* d_in, const int* in_sizes, int n_in,
                              void* d_out, int out_size, void* d_ws, size_t ws_size,
                              hipStream_t stream) {
    const float* X = (const float*)d_in[0];
    const int* A = (const int*)d_in[1];
    const float* Wq = (const float*)d_in[2];
    const float* Wk = (const float*)d_in[3];
    const float* Wv = (const float*)d_in[4];
    float* out = (float*)d_out;

    char* ws = (char*)d_ws;
    const size_t MB = 1ull << 20;
    f16* Xh = (f16*)(ws + 0 * MB);
    f16* Xl = (f16*)(ws + 4 * MB);
    f16* WtH = (f16*)(ws + 8 * MB);
    f16* WtL = (f16*)(ws + 8 * MB + 512 * 1024);
    f16* Qh = (f16*)(ws + 9 * MB);
    f16* Ql = (f16*)(ws + 13 * MB);
    f16* Kh = (f16*)(ws + 17 * MB);
    f16* Vt = (f16*)(ws + 21 * MB);
    float* pO = (float*)(ws + 25 * MB);
    float* pM = (float*)(ws + 57 * MB);
    float* pL = (float*)(ws + 57 * MB + 256 * 1024);
    (void)ws_size; (void)in_sizes; (void)n_in; (void)out_size;

    prep_kernel<<<2816, 256, 0, stream>>>((const float4*)X, (f16x4*)Xh, (f16x4*)Xl,
                                          Wq, Wk, Wv, WtH, WtL);
    qkv_kernel<<<dim3(NN / 64, 3), 256, 0, stream>>>(Xh, Xl, WtH, WtL, Qh, Ql, Kh, Vt);
    flash_kernel<<<(NN / BR) * CCH, 512, 0, stream>>>(Qh, Ql, Kh, Vt, A, pO, pM, pL);
    merge_kernel<<<NN / 8, 256, 0, stream>>>(pO, pM, pL, out);
}